// Round 3
// baseline (1456.284 us; speedup 1.0000x reference)
//
#include <hip/hip_runtime.h>
#include <stdint.h>

typedef unsigned short u16;
typedef __bf16 bf16x8 __attribute__((ext_vector_type(8)));
typedef float f32x4 __attribute__((ext_vector_type(4)));

#define NNODES 150000
#define KNBR 27
#define LDX 128
#define MROWS 64
#define APAD 72    // conv1 LDS row stride (u16): 144B -> 4-bank row rotation, free 2-way
#define UPAD 136   // conv2 LDS row stride (u16): 272B -> same rotation property

static __device__ __forceinline__ u16 f2bf(float f){
  union { float f; uint32_t i; } v; v.f = f;
  uint32_t x = v.i;
  uint32_t r = (x + 0x7fffu + ((x >> 16) & 1u)) >> 16;  // RNE
  return (u16)r;
}
static __device__ __forceinline__ float lrelu(float v){ return v >= 0.f ? v : 0.2f*v; }

// fp32 weight (krows x 64) -> bf16 MFMA B-fragment order
__global__ void reformat_w(const float* __restrict__ src, u16* __restrict__ dst, int ksteps){
  int idx = blockIdx.x*256 + threadIdx.x;
  int total = ksteps*4*64;
  if (idx >= total) return;
  int lane = idx & 63;
  int ctile = (idx >> 6) & 3;
  int t = idx >> 8;
  int quad = lane >> 4, m = lane & 15;
  union { u16 h[8]; float4 v; } tmp;
  const float* s = src + ((size_t)(t*32 + quad*8))*64 + ctile*16 + m;
  #pragma unroll
  for (int j=0;j<8;j++) tmp.h[j] = f2bf(s[j*64]);
  *reinterpret_cast<float4*>(dst + (size_t)idx*8) = tmp.v;
}

// x cols 64..127 (fp32, LDX stride) -> bf16 table sb (N x 64). 8 elems/thread.
__global__ void conv_x2(const float* __restrict__ x, u16* __restrict__ sb){
  int idx = blockIdx.x*256 + threadIdx.x;
  int e = idx*8;
  if (e >= NNODES*64) return;
  int row = e >> 6, col = e & 63;
  const float* s = x + (size_t)row*LDX + 64 + col;
  float4 a = *reinterpret_cast<const float4*>(s);
  float4 b = *reinterpret_cast<const float4*>(s+4);
  union { u16 h[8]; float4 v; } t;
  t.h[0]=f2bf(a.x); t.h[1]=f2bf(a.y); t.h[2]=f2bf(a.z); t.h[3]=f2bf(a.w);
  t.h[4]=f2bf(b.x); t.h[5]=f2bf(b.y); t.h[6]=f2bf(b.z); t.h[7]=f2bf(b.w);
  *reinterpret_cast<float4*>(sb + e) = t.v;
}

// u[:,0:64] = lrelu(lrelu(gather(sb) @ w1g) @ w2g); u[:,64:128] = same with h weights.
// sb bf16 (N x 64); u bf16 (N x 128) interleaved [g|h].
__global__ __launch_bounds__(256) void conv1_fused(
    const u16* __restrict__ sb,
    const int* __restrict__ nbr,
    const u16* __restrict__ wb1g, const u16* __restrict__ wb1h,
    const u16* __restrict__ wb2g, const u16* __restrict__ wb2h,
    u16* __restrict__ u)
{
  __shared__ int s_idx[MROWS*KNBR];
  __shared__ u16 s_a[2][MROWS*APAD];

  int tid = threadIdx.x;
  int row0 = blockIdx.x * MROWS;
  for (int i = tid; i < MROWS*KNBR; i += 256){
    int r = i / KNBR, kk = i - r*KNBR;
    int row = row0 + r;
    s_idx[i] = (row < NNODES) ? nbr[row*KNBR + kk] : 0;
  }
  __syncthreads();

  int lane = tid & 63;
  int wv = tid >> 6;
  int quad = lane >> 4, m = lane & 15;
  int r0w = wv * 16;

  f32x4 accg[4], acch[4];
  f32x4 zz = {0.f,0.f,0.f,0.f};
  #pragma unroll
  for (int i=0;i<4;i++){ accg[i]=zz; acch[i]=zz; }

  // gather: 16B chunks; chunk0 row tid>>3 (0..31), chunk1 row +32
  int gr0 = tid >> 3, gs = (tid & 7) * 8;
  int gr1 = gr0 + 32;

  float4 p0, p1;
  {
    int f0 = s_idx[gr0*KNBR], f1 = s_idx[gr1*KNBR];
    p0 = *reinterpret_cast<const float4*>(sb + (size_t)f0*64 + gs);
    p1 = *reinterpret_cast<const float4*>(sb + (size_t)f1*64 + gs);
  }

  for (int k=0;k<KNBR;k++){
    u16* buf = s_a[k&1];
    *reinterpret_cast<float4*>(&buf[gr0*APAD + gs]) = p0;
    *reinterpret_cast<float4*>(&buf[gr1*APAD + gs]) = p1;
    if (k+1 < KNBR){
      int f0 = s_idx[gr0*KNBR + k+1], f1 = s_idx[gr1*KNBR + k+1];
      p0 = *reinterpret_cast<const float4*>(sb + (size_t)f0*64 + gs);
      p1 = *reinterpret_cast<const float4*>(sb + (size_t)f1*64 + gs);
    }
    __syncthreads();
    #pragma unroll
    for (int c=0;c<2;c++){
      bf16x8 afrag = *reinterpret_cast<const bf16x8*>(&buf[(r0w+m)*APAD + c*32 + quad*8]);
      int t = k*2 + c;
      #pragma unroll
      for (int ct=0;ct<4;ct++){
        bf16x8 bg = *reinterpret_cast<const bf16x8*>(wb1g + (((size_t)t*4+ct)*64 + lane)*8);
        accg[ct] = __builtin_amdgcn_mfma_f32_16x16x32_bf16(afrag, bg, accg[ct], 0,0,0);
        bf16x8 bh = *reinterpret_cast<const bf16x8*>(wb1h + (((size_t)t*4+ct)*64 + lane)*8);
        acch[ct] = __builtin_amdgcn_mfma_f32_16x16x32_bf16(afrag, bh, acch[ct], 0,0,0);
      }
    }
  }
  __syncthreads();

  // lrelu -> bf16 tiles in LDS (C-layout -> A-layout round trip)
  #pragma unroll
  for (int ct=0;ct<4;ct++){
    #pragma unroll
    for (int i=0;i<4;i++){
      int rl = r0w + quad*4 + i;
      int col = ct*16 + m;
      s_a[0][rl*APAD + col] = f2bf(lrelu(accg[ct][i]));
      s_a[1][rl*APAD + col] = f2bf(lrelu(acch[ct][i]));
    }
  }
  __syncthreads();

  f32x4 dg[4], dh[4];
  #pragma unroll
  for (int i=0;i<4;i++){ dg[i]=zz; dh[i]=zz; }
  #pragma unroll
  for (int c=0;c<2;c++){
    bf16x8 ag = *reinterpret_cast<const bf16x8*>(&s_a[0][(r0w+m)*APAD + c*32 + quad*8]);
    bf16x8 ah = *reinterpret_cast<const bf16x8*>(&s_a[1][(r0w+m)*APAD + c*32 + quad*8]);
    #pragma unroll
    for (int ct=0;ct<4;ct++){
      bf16x8 bg = *reinterpret_cast<const bf16x8*>(wb2g + (((size_t)c*4+ct)*64 + lane)*8);
      dg[ct] = __builtin_amdgcn_mfma_f32_16x16x32_bf16(ag, bg, dg[ct], 0,0,0);
      bf16x8 bh = *reinterpret_cast<const bf16x8*>(wb2h + (((size_t)c*4+ct)*64 + lane)*8);
      dh[ct] = __builtin_amdgcn_mfma_f32_16x16x32_bf16(ah, bh, dh[ct], 0,0,0);
    }
  }
  #pragma unroll
  for (int ct=0;ct<4;ct++){
    #pragma unroll
    for (int i=0;i<4;i++){
      int row = row0 + r0w + quad*4 + i;
      if (row < NNODES){
        int col = ct*16 + m;
        u[(size_t)row*128 + col]      = f2bf(lrelu(dg[ct][i]));
        u[(size_t)row*128 + 64 + col] = f2bf(lrelu(dh[ct][i]));
      }
    }
  }
}

// bg = gather(u[:,:64]) @ w3g ; bh = gather(u[:,64:]) @ w3h ;
// y = x_prev * exp(2*sigmoid(bg)-1) + bh -> out fp32; optionally y -> yb bf16.
__global__ __launch_bounds__(256) void conv2_coupling(
    const u16* __restrict__ u,
    const int* __restrict__ nbr,
    const u16* __restrict__ wbg, const u16* __restrict__ wbh,
    const float* __restrict__ x, int xcol0,
    float* __restrict__ out, int ycol0,
    u16* __restrict__ yb, int write_yb)
{
  __shared__ int s_idx[MROWS*KNBR];
  __shared__ u16 s_u[2][MROWS*UPAD];

  int tid = threadIdx.x;
  int row0 = blockIdx.x * MROWS;
  for (int i = tid; i < MROWS*KNBR; i += 256){
    int r = i / KNBR, kk = i - r*KNBR;
    int row = row0 + r;
    s_idx[i] = (row < NNODES) ? nbr[row*KNBR + kk] : 0;
  }
  __syncthreads();

  int lane = tid & 63;
  int wv = tid >> 6;
  int quad = lane >> 4, m = lane & 15;
  int r0w = wv * 16;

  f32x4 accg[4], acch[4];
  f32x4 zz = {0.f,0.f,0.f,0.f};
  #pragma unroll
  for (int i=0;i<4;i++){ accg[i]=zz; acch[i]=zz; }

  // gather: 256B rows; 16 threads/row; 4 chunks = rows gr, gr+16, gr+32, gr+48
  int gr = tid >> 4, gs = (tid & 15) * 8;

  float4 p[4];
  #pragma unroll
  for (int j=0;j<4;j++){
    int f = s_idx[(gr + 16*j)*KNBR];
    p[j] = *reinterpret_cast<const float4*>(u + (size_t)f*128 + gs);
  }

  for (int k=0;k<KNBR;k++){
    u16* buf = s_u[k&1];
    #pragma unroll
    for (int j=0;j<4;j++)
      *reinterpret_cast<float4*>(&buf[(gr + 16*j)*UPAD + gs]) = p[j];
    if (k+1 < KNBR){
      #pragma unroll
      for (int j=0;j<4;j++){
        int f = s_idx[(gr + 16*j)*KNBR + k+1];
        p[j] = *reinterpret_cast<const float4*>(u + (size_t)f*128 + gs);
      }
    }
    __syncthreads();
    #pragma unroll
    for (int c=0;c<2;c++){
      bf16x8 ag = *reinterpret_cast<const bf16x8*>(&buf[(r0w+m)*UPAD + c*32 + quad*8]);
      bf16x8 ah = *reinterpret_cast<const bf16x8*>(&buf[(r0w+m)*UPAD + 64 + c*32 + quad*8]);
      int t = k*2 + c;
      #pragma unroll
      for (int ct=0;ct<4;ct++){
        bf16x8 bg = *reinterpret_cast<const bf16x8*>(wbg + (((size_t)t*4+ct)*64 + lane)*8);
        accg[ct] = __builtin_amdgcn_mfma_f32_16x16x32_bf16(ag, bg, accg[ct], 0,0,0);
        bf16x8 bh = *reinterpret_cast<const bf16x8*>(wbh + (((size_t)t*4+ct)*64 + lane)*8);
        acch[ct] = __builtin_amdgcn_mfma_f32_16x16x32_bf16(ah, bh, acch[ct], 0,0,0);
      }
    }
  }

  #pragma unroll
  for (int ct=0;ct<4;ct++){
    #pragma unroll
    for (int i=0;i<4;i++){
      int row = row0 + r0w + quad*4 + i;
      if (row < NNODES){
        int col = ct*16 + m;
        float bg = accg[ct][i];
        float bh = acch[ct][i];
        float s = 1.f/(1.f + __expf(-bg));
        s = __expf(2.f*s - 1.f);
        float xv = x[(size_t)row*LDX + xcol0 + col];
        float y = xv*s + bh;
        out[(size_t)row*LDX + ycol0 + col] = y;
        if (write_yb) yb[(size_t)row*64 + col] = f2bf(y);
      }
    }
  }
}

extern "C" void kernel_launch(void* const* d_in, const int* in_sizes, int n_in,
                              void* d_out, int out_size, void* d_ws, size_t ws_size,
                              hipStream_t stream)
{
  const float* x   = (const float*)d_in[0];
  const int*   nbr = (const int*)d_in[1];
  const float* g1_w1=(const float*)d_in[2],  *g1_w2=(const float*)d_in[3],  *g1_w3=(const float*)d_in[4];
  const float* g2_w1=(const float*)d_in[5],  *g2_w2=(const float*)d_in[6],  *g2_w3=(const float*)d_in[7];
  const float* h1_w1=(const float*)d_in[8],  *h1_w2=(const float*)d_in[9],  *h1_w3=(const float*)d_in[10];
  const float* h2_w1=(const float*)d_in[11], *h2_w2=(const float*)d_in[12], *h2_w3=(const float*)d_in[13];
  float* out = (float*)d_out;
  u16* ws = (u16*)d_ws;

  const size_t WBB = (size_t)54*4*64*8;  // 1728-row weights (bf16 frags)
  const size_t WBS = (size_t)2*4*64*8;   // 64-row weights
  u16* p = ws;
  u16* wb_g2_1=p; p+=WBB;  u16* wb_h2_1=p; p+=WBB;
  u16* wb_g2_2=p; p+=WBS;  u16* wb_h2_2=p; p+=WBS;
  u16* wb_g2_3=p; p+=WBB;  u16* wb_h2_3=p; p+=WBB;
  u16* wb_g1_1=p; p+=WBB;  u16* wb_h1_1=p; p+=WBB;
  u16* wb_g1_2=p; p+=WBS;  u16* wb_h1_2=p; p+=WBS;
  u16* wb_g1_3=p; p+=WBB;  u16* wb_h1_3=p; p+=WBB;
  u16* ub = p; p += (size_t)NNODES*128;   // interleaved [g|h] bf16
  u16* sb = p; p += (size_t)NNODES*64;    // gather source table (x2 bf16, then y1 bf16)

  reformat_w<<<54,256,0,stream>>>(g2_w1, wb_g2_1, 54);
  reformat_w<<<54,256,0,stream>>>(h2_w1, wb_h2_1, 54);
  reformat_w<<<2,256,0,stream>>>(g2_w2, wb_g2_2, 2);
  reformat_w<<<2,256,0,stream>>>(h2_w2, wb_h2_2, 2);
  reformat_w<<<54,256,0,stream>>>(g2_w3, wb_g2_3, 54);
  reformat_w<<<54,256,0,stream>>>(h2_w3, wb_h2_3, 54);
  reformat_w<<<54,256,0,stream>>>(g1_w1, wb_g1_1, 54);
  reformat_w<<<54,256,0,stream>>>(h1_w1, wb_h1_1, 54);
  reformat_w<<<2,256,0,stream>>>(g1_w2, wb_g1_2, 2);
  reformat_w<<<2,256,0,stream>>>(h1_w2, wb_h1_2, 2);
  reformat_w<<<54,256,0,stream>>>(g1_w3, wb_g1_3, 54);
  reformat_w<<<54,256,0,stream>>>(h1_w3, wb_h1_3, 54);

  conv_x2<<<(NNODES*64/8 + 255)/256, 256, 0, stream>>>(x, sb);

  int nblk = (NNODES + MROWS - 1)/MROWS;  // 2344
  // Phase A: sb = x2(bf16); y1 -> out cols 0..63 + sb(bf16)
  conv1_fused<<<nblk,256,0,stream>>>(sb, nbr, wb_g2_1, wb_h2_1, wb_g2_2, wb_h2_2, ub);
  conv2_coupling<<<nblk,256,0,stream>>>(ub, nbr, wb_g2_3, wb_h2_3, x, 0, out, 0, sb, 1);
  // Phase B: sb = y1(bf16); y2 -> out cols 64..127
  conv1_fused<<<nblk,256,0,stream>>>(sb, nbr, wb_g1_1, wb_h1_1, wb_g1_2, wb_h1_2, ub);
  conv2_coupling<<<nblk,256,0,stream>>>(ub, nbr, wb_g1_3, wb_h1_3, x, 64, out, 64, sb, 0);
}

// Round 4
// 1140.060 us; speedup vs baseline: 1.2774x; 1.2774x over previous
//
#include <hip/hip_runtime.h>
#include <stdint.h>

typedef unsigned short u16;
typedef __bf16 bf16x8 __attribute__((ext_vector_type(8)));
typedef float f32x4 __attribute__((ext_vector_type(4)));

#define NNODES 150000
#define KNBR 27
#define LDX 128
#define MROWS 64
#define APAD 72   // epilogue LDS row stride (u16)

static __device__ __forceinline__ u16 f2bf(float f){
  union { float f; uint32_t i; } v; v.f = f;
  uint32_t x = v.i;
  uint32_t r = (x + 0x7fffu + ((x >> 16) & 1u)) >> 16;  // RNE
  return (u16)r;
}
static __device__ __forceinline__ float lrelu(float v){ return v >= 0.f ? v : 0.2f*v; }

// fp32 weight (krows x 64) -> bf16 MFMA B-fragment order
__global__ void reformat_w(const float* __restrict__ src, u16* __restrict__ dst, int ksteps){
  int idx = blockIdx.x*256 + threadIdx.x;
  int total = ksteps*4*64;
  if (idx >= total) return;
  int lane = idx & 63;
  int ctile = (idx >> 6) & 3;
  int t = idx >> 8;
  int quad = lane >> 4, m = lane & 15;
  union { u16 h[8]; float4 v; } tmp;
  const float* s = src + ((size_t)(t*32 + quad*8))*64 + ctile*16 + m;
  #pragma unroll
  for (int j=0;j<8;j++) tmp.h[j] = f2bf(s[j*64]);
  *reinterpret_cast<float4*>(dst + (size_t)idx*8) = tmp.v;
}

// x cols 64..127 (fp32, LDX stride) -> bf16 table sb (N x 64)
__global__ void conv_x2(const float* __restrict__ x, u16* __restrict__ sb){
  int idx = blockIdx.x*256 + threadIdx.x;
  int e = idx*8;
  if (e >= NNODES*64) return;
  int row = e >> 6, col = e & 63;
  const float* s = x + (size_t)row*LDX + 64 + col;
  float4 a = *reinterpret_cast<const float4*>(s);
  float4 b = *reinterpret_cast<const float4*>(s+4);
  union { u16 h[8]; float4 v; } t;
  t.h[0]=f2bf(a.x); t.h[1]=f2bf(a.y); t.h[2]=f2bf(a.z); t.h[3]=f2bf(a.w);
  t.h[4]=f2bf(b.x); t.h[5]=f2bf(b.y); t.h[6]=f2bf(b.z); t.h[7]=f2bf(b.w);
  *reinterpret_cast<float4*>(sb + e) = t.v;
}

// u[:,0:64] = lrelu(lrelu(gather(sb) @ w1g) @ w2g); u[:,64:128] = h-version.
// Direct per-lane A-fragment gather: no LDS staging in k-loop, no barriers.
__global__ __launch_bounds__(256,4) void conv1_fused(
    const u16* __restrict__ sb,
    const int* __restrict__ nbr,
    const u16* __restrict__ wb1g, const u16* __restrict__ wb1h,
    const u16* __restrict__ wb2g, const u16* __restrict__ wb2h,
    u16* __restrict__ u)
{
  __shared__ int s_idx[MROWS*KNBR];
  __shared__ u16 s_a[2][MROWS*APAD];

  int tid = threadIdx.x;
  int row0 = blockIdx.x * MROWS;
  for (int i = tid; i < MROWS*KNBR; i += 256){
    int r = i / KNBR, kk = i - r*KNBR;
    int row = row0 + r;
    s_idx[i] = (row < NNODES) ? nbr[row*KNBR + kk] : 0;
  }
  __syncthreads();

  int lane = tid & 63;
  int wv = tid >> 6;
  int quad = lane >> 4, m = lane & 15;
  int r0w = wv * 16;
  int qoff = quad * 8;
  const int* myidx = &s_idx[(r0w + m)*KNBR];

  f32x4 accg[4], acch[4];
  f32x4 zz = {0.f,0.f,0.f,0.f};
  #pragma unroll
  for (int i=0;i<4;i++){ accg[i]=zz; acch[i]=zz; }

  // 3-stage pipeline: a0 = frags for k, a1 = frags for k+1
  bf16x8 a0[2], a1[2];
  {
    const u16* s0 = sb + (size_t)myidx[0]*64 + qoff;
    a0[0] = *reinterpret_cast<const bf16x8*>(s0);
    a0[1] = *reinterpret_cast<const bf16x8*>(s0 + 32);
    const u16* s1 = sb + (size_t)myidx[1]*64 + qoff;
    a1[0] = *reinterpret_cast<const bf16x8*>(s1);
    a1[1] = *reinterpret_cast<const bf16x8*>(s1 + 32);
  }

  for (int k=0;k<KNBR;k++){
    bf16x8 c0 = a0[0], c1 = a0[1];
    a0[0] = a1[0]; a0[1] = a1[1];
    if (k+2 < KNBR){
      const u16* sn = sb + (size_t)myidx[k+2]*64 + qoff;
      a1[0] = *reinterpret_cast<const bf16x8*>(sn);
      a1[1] = *reinterpret_cast<const bf16x8*>(sn + 32);
    }
    #pragma unroll
    for (int c=0;c<2;c++){
      bf16x8 af = c ? c1 : c0;
      int t = k*2 + c;
      #pragma unroll
      for (int ct=0;ct<4;ct++){
        bf16x8 bg = *reinterpret_cast<const bf16x8*>(wb1g + (((size_t)t*4+ct)*64 + lane)*8);
        accg[ct] = __builtin_amdgcn_mfma_f32_16x16x32_bf16(af, bg, accg[ct], 0,0,0);
        bf16x8 bh = *reinterpret_cast<const bf16x8*>(wb1h + (((size_t)t*4+ct)*64 + lane)*8);
        acch[ct] = __builtin_amdgcn_mfma_f32_16x16x32_bf16(af, bh, acch[ct], 0,0,0);
      }
    }
  }
  __syncthreads();

  // lrelu -> bf16 tiles in LDS (C-layout -> A-layout round trip)
  #pragma unroll
  for (int ct=0;ct<4;ct++){
    #pragma unroll
    for (int i=0;i<4;i++){
      int rl = r0w + quad*4 + i;
      int col = ct*16 + m;
      s_a[0][rl*APAD + col] = f2bf(lrelu(accg[ct][i]));
      s_a[1][rl*APAD + col] = f2bf(lrelu(acch[ct][i]));
    }
  }
  __syncthreads();

  f32x4 dg[4], dh[4];
  #pragma unroll
  for (int i=0;i<4;i++){ dg[i]=zz; dh[i]=zz; }
  #pragma unroll
  for (int c=0;c<2;c++){
    bf16x8 ag = *reinterpret_cast<const bf16x8*>(&s_a[0][(r0w+m)*APAD + c*32 + qoff]);
    bf16x8 ah = *reinterpret_cast<const bf16x8*>(&s_a[1][(r0w+m)*APAD + c*32 + qoff]);
    #pragma unroll
    for (int ct=0;ct<4;ct++){
      bf16x8 bg = *reinterpret_cast<const bf16x8*>(wb2g + (((size_t)c*4+ct)*64 + lane)*8);
      dg[ct] = __builtin_amdgcn_mfma_f32_16x16x32_bf16(ag, bg, dg[ct], 0,0,0);
      bf16x8 bh = *reinterpret_cast<const bf16x8*>(wb2h + (((size_t)c*4+ct)*64 + lane)*8);
      dh[ct] = __builtin_amdgcn_mfma_f32_16x16x32_bf16(ah, bh, dh[ct], 0,0,0);
    }
  }
  #pragma unroll
  for (int ct=0;ct<4;ct++){
    #pragma unroll
    for (int i=0;i<4;i++){
      int row = row0 + r0w + quad*4 + i;
      if (row < NNODES){
        int col = ct*16 + m;
        u[(size_t)row*128 + col]      = f2bf(lrelu(dg[ct][i]));
        u[(size_t)row*128 + 64 + col] = f2bf(lrelu(dh[ct][i]));
      }
    }
  }
}

// bg = gather(u[:,:64]) @ w3g ; bh = gather(u[:,64:]) @ w3h ;
// y = x_prev * exp(2*sigmoid(bg)-1) + bh -> out fp32; optionally y -> yb bf16.
__global__ __launch_bounds__(256,4) void conv2_coupling(
    const u16* __restrict__ u,
    const int* __restrict__ nbr,
    const u16* __restrict__ wbg, const u16* __restrict__ wbh,
    const float* __restrict__ x, int xcol0,
    float* __restrict__ out, int ycol0,
    u16* __restrict__ yb, int write_yb)
{
  __shared__ int s_idx[MROWS*KNBR];

  int tid = threadIdx.x;
  int row0 = blockIdx.x * MROWS;
  for (int i = tid; i < MROWS*KNBR; i += 256){
    int r = i / KNBR, kk = i - r*KNBR;
    int row = row0 + r;
    s_idx[i] = (row < NNODES) ? nbr[row*KNBR + kk] : 0;
  }
  __syncthreads();

  int lane = tid & 63;
  int wv = tid >> 6;
  int quad = lane >> 4, m = lane & 15;
  int r0w = wv * 16;
  int qoff = quad * 8;
  const int* myidx = &s_idx[(r0w + m)*KNBR];

  f32x4 accg[4], acch[4];
  f32x4 zz = {0.f,0.f,0.f,0.f};
  #pragma unroll
  for (int i=0;i<4;i++){ accg[i]=zz; acch[i]=zz; }

  // 3-stage pipeline: 4 frags per stage [g c0, g c1, h c0, h c1]
  bf16x8 a0[4], a1[4];
  {
    const u16* s0 = u + (size_t)myidx[0]*128 + qoff;
    a0[0] = *reinterpret_cast<const bf16x8*>(s0);
    a0[1] = *reinterpret_cast<const bf16x8*>(s0 + 32);
    a0[2] = *reinterpret_cast<const bf16x8*>(s0 + 64);
    a0[3] = *reinterpret_cast<const bf16x8*>(s0 + 96);
    const u16* s1 = u + (size_t)myidx[1]*128 + qoff;
    a1[0] = *reinterpret_cast<const bf16x8*>(s1);
    a1[1] = *reinterpret_cast<const bf16x8*>(s1 + 32);
    a1[2] = *reinterpret_cast<const bf16x8*>(s1 + 64);
    a1[3] = *reinterpret_cast<const bf16x8*>(s1 + 96);
  }

  for (int k=0;k<KNBR;k++){
    bf16x8 cg0 = a0[0], cg1 = a0[1], ch0 = a0[2], ch1 = a0[3];
    #pragma unroll
    for (int j=0;j<4;j++) a0[j] = a1[j];
    if (k+2 < KNBR){
      const u16* sn = u + (size_t)myidx[k+2]*128 + qoff;
      a1[0] = *reinterpret_cast<const bf16x8*>(sn);
      a1[1] = *reinterpret_cast<const bf16x8*>(sn + 32);
      a1[2] = *reinterpret_cast<const bf16x8*>(sn + 64);
      a1[3] = *reinterpret_cast<const bf16x8*>(sn + 96);
    }
    #pragma unroll
    for (int c=0;c<2;c++){
      bf16x8 ag = c ? cg1 : cg0;
      bf16x8 ah = c ? ch1 : ch0;
      int t = k*2 + c;
      #pragma unroll
      for (int ct=0;ct<4;ct++){
        bf16x8 bg = *reinterpret_cast<const bf16x8*>(wbg + (((size_t)t*4+ct)*64 + lane)*8);
        accg[ct] = __builtin_amdgcn_mfma_f32_16x16x32_bf16(ag, bg, accg[ct], 0,0,0);
        bf16x8 bh = *reinterpret_cast<const bf16x8*>(wbh + (((size_t)t*4+ct)*64 + lane)*8);
        acch[ct] = __builtin_amdgcn_mfma_f32_16x16x32_bf16(ah, bh, acch[ct], 0,0,0);
      }
    }
  }

  #pragma unroll
  for (int ct=0;ct<4;ct++){
    #pragma unroll
    for (int i=0;i<4;i++){
      int row = row0 + r0w + quad*4 + i;
      if (row < NNODES){
        int col = ct*16 + m;
        float bg = accg[ct][i];
        float bh = acch[ct][i];
        float s = 1.f/(1.f + __expf(-bg));
        s = __expf(2.f*s - 1.f);
        float xv = x[(size_t)row*LDX + xcol0 + col];
        float y = xv*s + bh;
        out[(size_t)row*LDX + ycol0 + col] = y;
        if (write_yb) yb[(size_t)row*64 + col] = f2bf(y);
      }
    }
  }
}

extern "C" void kernel_launch(void* const* d_in, const int* in_sizes, int n_in,
                              void* d_out, int out_size, void* d_ws, size_t ws_size,
                              hipStream_t stream)
{
  const float* x   = (const float*)d_in[0];
  const int*   nbr = (const int*)d_in[1];
  const float* g1_w1=(const float*)d_in[2],  *g1_w2=(const float*)d_in[3],  *g1_w3=(const float*)d_in[4];
  const float* g2_w1=(const float*)d_in[5],  *g2_w2=(const float*)d_in[6],  *g2_w3=(const float*)d_in[7];
  const float* h1_w1=(const float*)d_in[8],  *h1_w2=(const float*)d_in[9],  *h1_w3=(const float*)d_in[10];
  const float* h2_w1=(const float*)d_in[11], *h2_w2=(const float*)d_in[12], *h2_w3=(const float*)d_in[13];
  float* out = (float*)d_out;
  u16* ws = (u16*)d_ws;

  const size_t WBB = (size_t)54*4*64*8;  // 1728-row weights (bf16 frags)
  const size_t WBS = (size_t)2*4*64*8;   // 64-row weights
  u16* p = ws;
  u16* wb_g2_1=p; p+=WBB;  u16* wb_h2_1=p; p+=WBB;
  u16* wb_g2_2=p; p+=WBS;  u16* wb_h2_2=p; p+=WBS;
  u16* wb_g2_3=p; p+=WBB;  u16* wb_h2_3=p; p+=WBB;
  u16* wb_g1_1=p; p+=WBB;  u16* wb_h1_1=p; p+=WBB;
  u16* wb_g1_2=p; p+=WBS;  u16* wb_h1_2=p; p+=WBS;
  u16* wb_g1_3=p; p+=WBB;  u16* wb_h1_3=p; p+=WBB;
  u16* ub = p; p += (size_t)NNODES*128;   // interleaved [g|h] bf16
  u16* sb = p; p += (size_t)NNODES*64;    // gather source (x2 bf16, then y1 bf16)

  reformat_w<<<54,256,0,stream>>>(g2_w1, wb_g2_1, 54);
  reformat_w<<<54,256,0,stream>>>(h2_w1, wb_h2_1, 54);
  reformat_w<<<2,256,0,stream>>>(g2_w2, wb_g2_2, 2);
  reformat_w<<<2,256,0,stream>>>(h2_w2, wb_h2_2, 2);
  reformat_w<<<54,256,0,stream>>>(g2_w3, wb_g2_3, 54);
  reformat_w<<<54,256,0,stream>>>(h2_w3, wb_h2_3, 54);
  reformat_w<<<54,256,0,stream>>>(g1_w1, wb_g1_1, 54);
  reformat_w<<<54,256,0,stream>>>(h1_w1, wb_h1_1, 54);
  reformat_w<<<2,256,0,stream>>>(g1_w2, wb_g1_2, 2);
  reformat_w<<<2,256,0,stream>>>(h1_w2, wb_h1_2, 2);
  reformat_w<<<54,256,0,stream>>>(g1_w3, wb_g1_3, 54);
  reformat_w<<<54,256,0,stream>>>(h1_w3, wb_h1_3, 54);

  conv_x2<<<(NNODES*64/8 + 255)/256, 256, 0, stream>>>(x, sb);

  int nblk = (NNODES + MROWS - 1)/MROWS;  // 2344
  // Phase A: sb = x2(bf16); y1 -> out cols 0..63 + sb(bf16)
  conv1_fused<<<nblk,256,0,stream>>>(sb, nbr, wb_g2_1, wb_h2_1, wb_g2_2, wb_h2_2, ub);
  conv2_coupling<<<nblk,256,0,stream>>>(ub, nbr, wb_g2_3, wb_h2_3, x, 0, out, 0, sb, 1);
  // Phase B: sb = y1(bf16); y2 -> out cols 64..127
  conv1_fused<<<nblk,256,0,stream>>>(sb, nbr, wb_g1_1, wb_h1_1, wb_g1_2, wb_h1_2, ub);
  conv2_coupling<<<nblk,256,0,stream>>>(ub, nbr, wb_g1_3, wb_h1_3, x, 64, out, 64, sb, 0);
}

// Round 5
// 1098.974 us; speedup vs baseline: 1.3251x; 1.0374x over previous
//
#include <hip/hip_runtime.h>
#include <stdint.h>

typedef unsigned short u16;
typedef __bf16 bf16x8 __attribute__((ext_vector_type(8)));
typedef float f32x4 __attribute__((ext_vector_type(4)));

#define NNODES 150000
#define KNBR 27
#define LDX 128
#define MROWS 128   // rows per block; 4 waves x 32 rows (2 M-tiles of 16)
#define APAD 72     // epilogue LDS row stride (u16)

static __device__ __forceinline__ u16 f2bf(float f){
  union { float f; uint32_t i; } v; v.f = f;
  uint32_t x = v.i;
  uint32_t r = (x + 0x7fffu + ((x >> 16) & 1u)) >> 16;  // RNE
  return (u16)r;
}
static __device__ __forceinline__ float lrelu(float v){ return v >= 0.f ? v : 0.2f*v; }

// fp32 weight (krows x 64) -> bf16 MFMA B-fragment order
__global__ void reformat_w(const float* __restrict__ src, u16* __restrict__ dst, int ksteps){
  int idx = blockIdx.x*256 + threadIdx.x;
  int total = ksteps*4*64;
  if (idx >= total) return;
  int lane = idx & 63;
  int ctile = (idx >> 6) & 3;
  int t = idx >> 8;
  int quad = lane >> 4, m = lane & 15;
  union { u16 h[8]; float4 v; } tmp;
  const float* s = src + ((size_t)(t*32 + quad*8))*64 + ctile*16 + m;
  #pragma unroll
  for (int j=0;j<8;j++) tmp.h[j] = f2bf(s[j*64]);
  *reinterpret_cast<float4*>(dst + (size_t)idx*8) = tmp.v;
}

// x cols 64..127 (fp32, LDX stride) -> bf16 table sb (N x 64)
__global__ void conv_x2(const float* __restrict__ x, u16* __restrict__ sb){
  int idx = blockIdx.x*256 + threadIdx.x;
  int e = idx*8;
  if (e >= NNODES*64) return;
  int row = e >> 6, col = e & 63;
  const float* s = x + (size_t)row*LDX + 64 + col;
  float4 a = *reinterpret_cast<const float4*>(s);
  float4 b = *reinterpret_cast<const float4*>(s+4);
  union { u16 h[8]; float4 v; } t;
  t.h[0]=f2bf(a.x); t.h[1]=f2bf(a.y); t.h[2]=f2bf(a.z); t.h[3]=f2bf(a.w);
  t.h[4]=f2bf(b.x); t.h[5]=f2bf(b.y); t.h[6]=f2bf(b.z); t.h[7]=f2bf(b.w);
  *reinterpret_cast<float4*>(sb + e) = t.v;
}

// u[:,0:64] = lrelu(lrelu(gather(sb) @ w1g) @ w2g); u[:,64:128] = h-version.
// 32 rows/wave (2 M-tiles), direct per-lane A-frag gather, register pipeline.
// Dynamic LDS: union of s_idx (k-loop) and epilogue tiles.
__global__ __launch_bounds__(256,2) void conv1_fused(
    const u16* __restrict__ sb,
    const int* __restrict__ nbr,
    const u16* __restrict__ wb1g, const u16* __restrict__ wb1h,
    const u16* __restrict__ wb2g, const u16* __restrict__ wb2h,
    u16* __restrict__ u)
{
  extern __shared__ char smem[];
  int* s_idx = (int*)smem;                 // [MROWS*KNBR] = 13824 B
  u16* s_a   = (u16*)smem;                 // [2][MROWS*APAD] = 36864 B (after k-loop)

  int tid = threadIdx.x;
  int row0 = blockIdx.x * MROWS;
  for (int i = tid; i < MROWS*KNBR; i += 256){
    int r = i / KNBR, kk = i - r*KNBR;
    int row = row0 + r;
    s_idx[i] = (row < NNODES) ? nbr[row*KNBR + kk] : 0;
  }
  __syncthreads();

  int lane = tid & 63;
  int wv = tid >> 6;
  int quad = lane >> 4, m = lane & 15;
  int qoff = quad * 8;
  int wrow = wv * 32;                       // this wave's first row
  const int* idx0 = &s_idx[(wrow + m)*KNBR];       // M-tile 0
  const int* idx1 = &s_idx[(wrow + 16 + m)*KNBR];  // M-tile 1

  f32x4 accg[2][4], acch[2][4];
  f32x4 zz = {0.f,0.f,0.f,0.f};
  #pragma unroll
  for (int mt=0;mt<2;mt++)
    #pragma unroll
    for (int i=0;i<4;i++){ accg[mt][i]=zz; acch[mt][i]=zz; }

  // A stages: [mt*2+c] frags; cur=k, nxt=k+1
  bf16x8 ac[4], an[4], b0[8], b1[8];
  {
    const u16* r00 = sb + (size_t)idx0[0]*64 + qoff;
    const u16* r01 = sb + (size_t)idx1[0]*64 + qoff;
    ac[0] = *reinterpret_cast<const bf16x8*>(r00);
    ac[1] = *reinterpret_cast<const bf16x8*>(r00 + 32);
    ac[2] = *reinterpret_cast<const bf16x8*>(r01);
    ac[3] = *reinterpret_cast<const bf16x8*>(r01 + 32);
    const u16* r10 = sb + (size_t)idx0[1]*64 + qoff;
    const u16* r11 = sb + (size_t)idx1[1]*64 + qoff;
    an[0] = *reinterpret_cast<const bf16x8*>(r10);
    an[1] = *reinterpret_cast<const bf16x8*>(r10 + 32);
    an[2] = *reinterpret_cast<const bf16x8*>(r11);
    an[3] = *reinterpret_cast<const bf16x8*>(r11 + 32);
    // B for t=0
    #pragma unroll
    for (int ct=0;ct<4;ct++){
      b0[ct]   = *reinterpret_cast<const bf16x8*>(wb1g + (((size_t)0*4+ct)*64 + lane)*8);
      b0[4+ct] = *reinterpret_cast<const bf16x8*>(wb1h + (((size_t)0*4+ct)*64 + lane)*8);
    }
  }

  #pragma unroll
  for (int k=0;k<KNBR;k++){
    int t1 = k*2 + 1;
    // issue B(t1)
    #pragma unroll
    for (int ct=0;ct<4;ct++){
      b1[ct]   = *reinterpret_cast<const bf16x8*>(wb1g + (((size_t)t1*4+ct)*64 + lane)*8);
      b1[4+ct] = *reinterpret_cast<const bf16x8*>(wb1h + (((size_t)t1*4+ct)*64 + lane)*8);
    }
    // issue A(k+2)
    bf16x8 at[4] = {ac[0],ac[1],ac[2],ac[3]};
    if (k+2 < KNBR){
      const u16* r0 = sb + (size_t)idx0[k+2]*64 + qoff;
      const u16* r1 = sb + (size_t)idx1[k+2]*64 + qoff;
      at[0] = *reinterpret_cast<const bf16x8*>(r0);
      at[1] = *reinterpret_cast<const bf16x8*>(r0 + 32);
      at[2] = *reinterpret_cast<const bf16x8*>(r1);
      at[3] = *reinterpret_cast<const bf16x8*>(r1 + 32);
    }
    // t0 = 2k: A frags c0 (ac[0], ac[2]) with b0
    #pragma unroll
    for (int ct=0;ct<4;ct++){
      accg[0][ct] = __builtin_amdgcn_mfma_f32_16x16x32_bf16(ac[0], b0[ct],   accg[0][ct], 0,0,0);
      acch[0][ct] = __builtin_amdgcn_mfma_f32_16x16x32_bf16(ac[0], b0[4+ct], acch[0][ct], 0,0,0);
      accg[1][ct] = __builtin_amdgcn_mfma_f32_16x16x32_bf16(ac[2], b0[ct],   accg[1][ct], 0,0,0);
      acch[1][ct] = __builtin_amdgcn_mfma_f32_16x16x32_bf16(ac[2], b0[4+ct], acch[1][ct], 0,0,0);
    }
    // issue B(t=2k+2) into b0 (for next iter's first MFMA set)
    if (k+1 < KNBR){
      int t2 = k*2 + 2;
      #pragma unroll
      for (int ct=0;ct<4;ct++){
        b0[ct]   = *reinterpret_cast<const bf16x8*>(wb1g + (((size_t)t2*4+ct)*64 + lane)*8);
        b0[4+ct] = *reinterpret_cast<const bf16x8*>(wb1h + (((size_t)t2*4+ct)*64 + lane)*8);
      }
    }
    // t1 = 2k+1: A frags c1 (ac[1], ac[3]) with b1
    #pragma unroll
    for (int ct=0;ct<4;ct++){
      accg[0][ct] = __builtin_amdgcn_mfma_f32_16x16x32_bf16(ac[1], b1[ct],   accg[0][ct], 0,0,0);
      acch[0][ct] = __builtin_amdgcn_mfma_f32_16x16x32_bf16(ac[1], b1[4+ct], acch[0][ct], 0,0,0);
      accg[1][ct] = __builtin_amdgcn_mfma_f32_16x16x32_bf16(ac[3], b1[ct],   accg[1][ct], 0,0,0);
      acch[1][ct] = __builtin_amdgcn_mfma_f32_16x16x32_bf16(ac[3], b1[4+ct], acch[1][ct], 0,0,0);
    }
    // rotate A stages
    #pragma unroll
    for (int j=0;j<4;j++){ ac[j] = an[j]; an[j] = at[j]; }
  }
  __syncthreads();   // s_idx dead; reuse LDS for epilogue tiles

  // lrelu -> bf16 tiles in LDS (C-layout -> A-layout round trip)
  u16* sa0 = s_a;
  u16* sa1 = s_a + MROWS*APAD;
  #pragma unroll
  for (int mt=0;mt<2;mt++){
    #pragma unroll
    for (int ct=0;ct<4;ct++){
      #pragma unroll
      for (int i=0;i<4;i++){
        int rl = wrow + mt*16 + quad*4 + i;
        int col = ct*16 + m;
        sa0[rl*APAD + col] = f2bf(lrelu(accg[mt][ct][i]));
        sa1[rl*APAD + col] = f2bf(lrelu(acch[mt][ct][i]));
      }
    }
  }
  __syncthreads();

  f32x4 dg[2][4], dh[2][4];
  #pragma unroll
  for (int mt=0;mt<2;mt++)
    #pragma unroll
    for (int i=0;i<4;i++){ dg[mt][i]=zz; dh[mt][i]=zz; }
  #pragma unroll
  for (int c=0;c<2;c++){
    #pragma unroll
    for (int mt=0;mt<2;mt++){
      bf16x8 ag = *reinterpret_cast<const bf16x8*>(&sa0[(wrow + mt*16 + m)*APAD + c*32 + qoff]);
      bf16x8 ah = *reinterpret_cast<const bf16x8*>(&sa1[(wrow + mt*16 + m)*APAD + c*32 + qoff]);
      #pragma unroll
      for (int ct=0;ct<4;ct++){
        bf16x8 bg = *reinterpret_cast<const bf16x8*>(wb2g + (((size_t)c*4+ct)*64 + lane)*8);
        dg[mt][ct] = __builtin_amdgcn_mfma_f32_16x16x32_bf16(ag, bg, dg[mt][ct], 0,0,0);
        bf16x8 bh = *reinterpret_cast<const bf16x8*>(wb2h + (((size_t)c*4+ct)*64 + lane)*8);
        dh[mt][ct] = __builtin_amdgcn_mfma_f32_16x16x32_bf16(ah, bh, dh[mt][ct], 0,0,0);
      }
    }
  }
  #pragma unroll
  for (int mt=0;mt<2;mt++){
    #pragma unroll
    for (int ct=0;ct<4;ct++){
      #pragma unroll
      for (int i=0;i<4;i++){
        int row = row0 + wrow + mt*16 + quad*4 + i;
        if (row < NNODES){
          int col = ct*16 + m;
          u[(size_t)row*128 + col]      = f2bf(lrelu(dg[mt][ct][i]));
          u[(size_t)row*128 + 64 + col] = f2bf(lrelu(dh[mt][ct][i]));
        }
      }
    }
  }
}

// bg = gather(u[:,:64]) @ w3g ; bh = gather(u[:,64:]) @ w3h ;
// y = x_prev * exp(2*sigmoid(bg)-1) + bh -> out fp32; optionally y -> yb bf16.
__global__ __launch_bounds__(256,2) void conv2_coupling(
    const u16* __restrict__ ub,
    const int* __restrict__ nbr,
    const u16* __restrict__ wbg, const u16* __restrict__ wbh,
    const float* __restrict__ x, int xcol0,
    float* __restrict__ out, int ycol0,
    u16* __restrict__ yb, int write_yb)
{
  __shared__ int s_idx[MROWS*KNBR];

  int tid = threadIdx.x;
  int row0 = blockIdx.x * MROWS;
  for (int i = tid; i < MROWS*KNBR; i += 256){
    int r = i / KNBR, kk = i - r*KNBR;
    int row = row0 + r;
    s_idx[i] = (row < NNODES) ? nbr[row*KNBR + kk] : 0;
  }
  __syncthreads();

  int lane = tid & 63;
  int wv = tid >> 6;
  int quad = lane >> 4, m = lane & 15;
  int qoff = quad * 8;
  int wrow = wv * 32;
  const int* idx0 = &s_idx[(wrow + m)*KNBR];
  const int* idx1 = &s_idx[(wrow + 16 + m)*KNBR];

  f32x4 accg[2][4], acch[2][4];
  f32x4 zz = {0.f,0.f,0.f,0.f};
  #pragma unroll
  for (int mt=0;mt<2;mt++)
    #pragma unroll
    for (int i=0;i<4;i++){ accg[mt][i]=zz; acch[mt][i]=zz; }

  // A stages: per k, 8 frags: [mt*4 + {g c0, g c1, h c0, h c1}]
  bf16x8 ac[8], an[8], b0[8], b1[8];
  {
    const u16* r0 = ub + (size_t)idx0[0]*128 + qoff;
    const u16* r1 = ub + (size_t)idx1[0]*128 + qoff;
    ac[0]=*reinterpret_cast<const bf16x8*>(r0);
    ac[1]=*reinterpret_cast<const bf16x8*>(r0+32);
    ac[2]=*reinterpret_cast<const bf16x8*>(r0+64);
    ac[3]=*reinterpret_cast<const bf16x8*>(r0+96);
    ac[4]=*reinterpret_cast<const bf16x8*>(r1);
    ac[5]=*reinterpret_cast<const bf16x8*>(r1+32);
    ac[6]=*reinterpret_cast<const bf16x8*>(r1+64);
    ac[7]=*reinterpret_cast<const bf16x8*>(r1+96);
    const u16* s0 = ub + (size_t)idx0[1]*128 + qoff;
    const u16* s1 = ub + (size_t)idx1[1]*128 + qoff;
    an[0]=*reinterpret_cast<const bf16x8*>(s0);
    an[1]=*reinterpret_cast<const bf16x8*>(s0+32);
    an[2]=*reinterpret_cast<const bf16x8*>(s0+64);
    an[3]=*reinterpret_cast<const bf16x8*>(s0+96);
    an[4]=*reinterpret_cast<const bf16x8*>(s1);
    an[5]=*reinterpret_cast<const bf16x8*>(s1+32);
    an[6]=*reinterpret_cast<const bf16x8*>(s1+64);
    an[7]=*reinterpret_cast<const bf16x8*>(s1+96);
    #pragma unroll
    for (int ct=0;ct<4;ct++){
      b0[ct]   = *reinterpret_cast<const bf16x8*>(wbg + (((size_t)0*4+ct)*64 + lane)*8);
      b0[4+ct] = *reinterpret_cast<const bf16x8*>(wbh + (((size_t)0*4+ct)*64 + lane)*8);
    }
  }

  #pragma unroll
  for (int k=0;k<KNBR;k++){
    int t1 = k*2 + 1;
    #pragma unroll
    for (int ct=0;ct<4;ct++){
      b1[ct]   = *reinterpret_cast<const bf16x8*>(wbg + (((size_t)t1*4+ct)*64 + lane)*8);
      b1[4+ct] = *reinterpret_cast<const bf16x8*>(wbh + (((size_t)t1*4+ct)*64 + lane)*8);
    }
    bf16x8 at[8] = {ac[0],ac[1],ac[2],ac[3],ac[4],ac[5],ac[6],ac[7]};
    if (k+2 < KNBR){
      const u16* r0 = ub + (size_t)idx0[k+2]*128 + qoff;
      const u16* r1 = ub + (size_t)idx1[k+2]*128 + qoff;
      at[0]=*reinterpret_cast<const bf16x8*>(r0);
      at[1]=*reinterpret_cast<const bf16x8*>(r0+32);
      at[2]=*reinterpret_cast<const bf16x8*>(r0+64);
      at[3]=*reinterpret_cast<const bf16x8*>(r0+96);
      at[4]=*reinterpret_cast<const bf16x8*>(r1);
      at[5]=*reinterpret_cast<const bf16x8*>(r1+32);
      at[6]=*reinterpret_cast<const bf16x8*>(r1+64);
      at[7]=*reinterpret_cast<const bf16x8*>(r1+96);
    }
    // t0 = 2k: g uses frag idx {0,4}(c0), h uses {2,6}(c0)
    #pragma unroll
    for (int ct=0;ct<4;ct++){
      accg[0][ct] = __builtin_amdgcn_mfma_f32_16x16x32_bf16(ac[0], b0[ct],   accg[0][ct], 0,0,0);
      acch[0][ct] = __builtin_amdgcn_mfma_f32_16x16x32_bf16(ac[2], b0[4+ct], acch[0][ct], 0,0,0);
      accg[1][ct] = __builtin_amdgcn_mfma_f32_16x16x32_bf16(ac[4], b0[ct],   accg[1][ct], 0,0,0);
      acch[1][ct] = __builtin_amdgcn_mfma_f32_16x16x32_bf16(ac[6], b0[4+ct], acch[1][ct], 0,0,0);
    }
    if (k+1 < KNBR){
      int t2 = k*2 + 2;
      #pragma unroll
      for (int ct=0;ct<4;ct++){
        b0[ct]   = *reinterpret_cast<const bf16x8*>(wbg + (((size_t)t2*4+ct)*64 + lane)*8);
        b0[4+ct] = *reinterpret_cast<const bf16x8*>(wbh + (((size_t)t2*4+ct)*64 + lane)*8);
      }
    }
    // t1 = 2k+1: g uses {1,5}(c1), h uses {3,7}(c1)
    #pragma unroll
    for (int ct=0;ct<4;ct++){
      accg[0][ct] = __builtin_amdgcn_mfma_f32_16x16x32_bf16(ac[1], b1[ct],   accg[0][ct], 0,0,0);
      acch[0][ct] = __builtin_amdgcn_mfma_f32_16x16x32_bf16(ac[3], b1[4+ct], acch[0][ct], 0,0,0);
      accg[1][ct] = __builtin_amdgcn_mfma_f32_16x16x32_bf16(ac[5], b1[ct],   accg[1][ct], 0,0,0);
      acch[1][ct] = __builtin_amdgcn_mfma_f32_16x16x32_bf16(ac[7], b1[4+ct], acch[1][ct], 0,0,0);
    }
    #pragma unroll
    for (int j=0;j<8;j++){ ac[j] = an[j]; an[j] = at[j]; }
  }

  #pragma unroll
  for (int mt=0;mt<2;mt++){
    #pragma unroll
    for (int ct=0;ct<4;ct++){
      #pragma unroll
      for (int i=0;i<4;i++){
        int row = row0 + wrow + mt*16 + quad*4 + i;
        if (row < NNODES){
          int col = ct*16 + m;
          float bg = accg[mt][ct][i];
          float bh = acch[mt][ct][i];
          float s = 1.f/(1.f + __expf(-bg));
          s = __expf(2.f*s - 1.f);
          float xv = x[(size_t)row*LDX + xcol0 + col];
          float y = xv*s + bh;
          out[(size_t)row*LDX + ycol0 + col] = y;
          if (write_yb) yb[(size_t)row*64 + col] = f2bf(y);
        }
      }
    }
  }
}

extern "C" void kernel_launch(void* const* d_in, const int* in_sizes, int n_in,
                              void* d_out, int out_size, void* d_ws, size_t ws_size,
                              hipStream_t stream)
{
  const float* x   = (const float*)d_in[0];
  const int*   nbr = (const int*)d_in[1];
  const float* g1_w1=(const float*)d_in[2],  *g1_w2=(const float*)d_in[3],  *g1_w3=(const float*)d_in[4];
  const float* g2_w1=(const float*)d_in[5],  *g2_w2=(const float*)d_in[6],  *g2_w3=(const float*)d_in[7];
  const float* h1_w1=(const float*)d_in[8],  *h1_w2=(const float*)d_in[9],  *h1_w3=(const float*)d_in[10];
  const float* h2_w1=(const float*)d_in[11], *h2_w2=(const float*)d_in[12], *h2_w3=(const float*)d_in[13];
  float* out = (float*)d_out;
  u16* ws = (u16*)d_ws;

  const size_t WBB = (size_t)54*4*64*8;  // 1728-row weights (bf16 frags)
  const size_t WBS = (size_t)2*4*64*8;   // 64-row weights
  u16* p = ws;
  u16* wb_g2_1=p; p+=WBB;  u16* wb_h2_1=p; p+=WBB;
  u16* wb_g2_2=p; p+=WBS;  u16* wb_h2_2=p; p+=WBS;
  u16* wb_g2_3=p; p+=WBB;  u16* wb_h2_3=p; p+=WBB;
  u16* wb_g1_1=p; p+=WBB;  u16* wb_h1_1=p; p+=WBB;
  u16* wb_g1_2=p; p+=WBS;  u16* wb_h1_2=p; p+=WBS;
  u16* wb_g1_3=p; p+=WBB;  u16* wb_h1_3=p; p+=WBB;
  u16* ub = p; p += (size_t)NNODES*128;   // interleaved [g|h] bf16
  u16* sb = p; p += (size_t)NNODES*64;    // gather source (x2 bf16, then y1 bf16)

  reformat_w<<<54,256,0,stream>>>(g2_w1, wb_g2_1, 54);
  reformat_w<<<54,256,0,stream>>>(h2_w1, wb_h2_1, 54);
  reformat_w<<<2,256,0,stream>>>(g2_w2, wb_g2_2, 2);
  reformat_w<<<2,256,0,stream>>>(h2_w2, wb_h2_2, 2);
  reformat_w<<<54,256,0,stream>>>(g2_w3, wb_g2_3, 54);
  reformat_w<<<54,256,0,stream>>>(h2_w3, wb_h2_3, 54);
  reformat_w<<<54,256,0,stream>>>(g1_w1, wb_g1_1, 54);
  reformat_w<<<54,256,0,stream>>>(h1_w1, wb_h1_1, 54);
  reformat_w<<<2,256,0,stream>>>(g1_w2, wb_g1_2, 2);
  reformat_w<<<2,256,0,stream>>>(h1_w2, wb_h1_2, 2);
  reformat_w<<<54,256,0,stream>>>(g1_w3, wb_g1_3, 54);
  reformat_w<<<54,256,0,stream>>>(h1_w3, wb_h1_3, 54);

  conv_x2<<<(NNODES*64/8 + 255)/256, 256, 0, stream>>>(x, sb);

  int nblk = (NNODES + MROWS - 1)/MROWS;  // 1172
  size_t c1_lds = (size_t)2*MROWS*APAD*2; // 36864 B (>= s_idx 13824 B)
  // Phase A: sb = x2(bf16); y1 -> out cols 0..63 + sb(bf16)
  conv1_fused<<<nblk,256,c1_lds,stream>>>(sb, nbr, wb_g2_1, wb_h2_1, wb_g2_2, wb_h2_2, ub);
  conv2_coupling<<<nblk,256,0,stream>>>(ub, nbr, wb_g2_3, wb_h2_3, x, 0, out, 0, sb, 1);
  // Phase B: sb = y1(bf16); y2 -> out cols 64..127
  conv1_fused<<<nblk,256,c1_lds,stream>>>(sb, nbr, wb_g1_1, wb_h1_1, wb_g1_2, wb_h1_2, ub);
  conv2_coupling<<<nblk,256,0,stream>>>(ub, nbr, wb_g1_3, wb_h1_3, x, 64, out, 64, sb, 0);
}